// Round 12
// baseline (409.622 us; speedup 1.0000x reference)
//
#include <hip/hip_runtime.h>
#include <hip/hip_bf16.h>

#ifndef D_FEAT
#define D_FEAT 128
#endif

typedef __attribute__((ext_vector_type(8))) short bf16x8;
typedef __attribute__((ext_vector_type(4))) float f32x4;
typedef unsigned long long u64;

// ---------------- bf16 helpers (RN-even) ----------------
__device__ __forceinline__ unsigned short f2bf(float f) {
    union { float f; unsigned u; } v; v.f = f;
    unsigned r = v.u + 0x7FFF + ((v.u >> 16) & 1);
    return (unsigned short)(r >> 16);
}
__device__ __forceinline__ float bf2f_lo(unsigned u) {
    union { unsigned u; float f; } v; v.u = u << 16; return v.f;
}
__device__ __forceinline__ float bf2f_hi(unsigned u) {
    union { unsigned u; float f; } v; v.u = u & 0xFFFF0000u; return v.f;
}
__device__ __forceinline__ float bfu(unsigned short s) {
    union { unsigned u; float f; } v; v.u = ((unsigned)s) << 16; return v.f;
}

__device__ __forceinline__ int sel8_i(int p, int a0, int a1, int a2, int a3,
                                      int a4, int a5, int a6, int a7) {
    int r = a0;
    r = (p == 1) ? a1 : r; r = (p == 2) ? a2 : r; r = (p == 3) ? a3 : r;
    r = (p == 4) ? a4 : r; r = (p == 5) ? a5 : r; r = (p == 6) ? a6 : r;
    r = (p == 7) ? a7 : r;
    return r;
}
__device__ __forceinline__ u64 sel8_u64(int p, u64 a0, u64 a1, u64 a2, u64 a3,
                                        u64 a4, u64 a5, u64 a6, u64 a7) {
    u64 r = a0;
    r = (p == 1) ? a1 : r; r = (p == 2) ? a2 : r; r = (p == 3) ? a3 : r;
    r = (p == 4) ? a4 : r; r = (p == 5) ? a5 : r; r = (p == 6) ? a6 : r;
    r = (p == 7) ? a7 : r;
    return r;
}

// ---------------------------------------------------------------------------
// Scan kernels for per-node CSR offsets (row_ptr, pos insert cursors).
// ---------------------------------------------------------------------------
__global__ void scan_block_sums(const int* __restrict__ counts, int* __restrict__ bsum, int N) {
    __shared__ int red[256];
    const int b = blockIdx.x, t = threadIdx.x;
    const int base = b * 1024 + t * 4;
    int s = 0;
#pragma unroll
    for (int j = 0; j < 4; ++j) { int i = base + j; if (i < N) s += counts[i]; }
    red[t] = s; __syncthreads();
    for (int off = 128; off > 0; off >>= 1) {
        if (t < off) red[t] += red[t + off];
        __syncthreads();
    }
    if (t == 0) bsum[b] = red[0];
}

__global__ void scan_offsets(int* __restrict__ bsum, int nb, int* __restrict__ row_ptr, int N) {
    __shared__ int sh[128];
    const int t = threadIdx.x;
    const int v = (t < nb) ? bsum[t] : 0;
    sh[t] = v; __syncthreads();
    for (int off = 1; off < 128; off <<= 1) {
        int add = (t >= off) ? sh[t - off] : 0;
        __syncthreads();
        sh[t] += add;
        __syncthreads();
    }
    const int incl = sh[t];
    if (t < nb) bsum[t] = incl - v;
    if (t == nb - 1) row_ptr[N] = incl;
}

__global__ void scan_final(const int* __restrict__ counts, const int* __restrict__ bsum,
                           int* __restrict__ row_ptr, int* __restrict__ pos, int N) {
    __shared__ int tsum[256];
    const int b = blockIdx.x, t = threadIdx.x;
    const int base = b * 1024 + t * 4;
    int c[4]; int s = 0;
#pragma unroll
    for (int j = 0; j < 4; ++j) { int i = base + j; c[j] = (i < N) ? counts[i] : 0; s += c[j]; }
    tsum[t] = s; __syncthreads();
    const int v = s;
    for (int off = 1; off < 256; off <<= 1) {
        int add = (t >= off) ? tsum[t - off] : 0;
        __syncthreads();
        tsum[t] += add;
        __syncthreads();
    }
    int excl = tsum[t] - v + bsum[b];
#pragma unroll
    for (int j = 0; j < 4; ++j) {
        int i = base + j;
        if (i < N) { row_ptr[i] = excl; pos[i] = excl; excl += c[j]; }
    }
}

// ---------------------------------------------------------------------------
// Single-pass ballot-routed 8-way bucket split (NO per-node histogram here —
// cross-XCD atomics onto counts[] were the 85us cost; hist moved to the
// partition-confined bucket pass below).
// Record: src | dst<<20 | bf16(w)<<40  (N < 2^20).
// ---------------------------------------------------------------------------
#define CH 512

__global__ void init_pcur(int* __restrict__ pcur, int cap) {
    if (threadIdx.x < 8) pcur[threadIdx.x] = threadIdx.x * cap;
}

__global__ void __launch_bounds__(256)
split_edges(const int* __restrict__ src, const int* __restrict__ dst,
            const float* __restrict__ ew, int E, int Q,
            int* __restrict__ pcur,      // 8 cursors, init p*cap
            u64* __restrict__ stg) {
    __shared__ int cw[4][8];   // per-wave partition counts
    __shared__ int wb[4][8];   // per-wave partition bases
    const int t = threadIdx.x;
    const int w = t >> 6;
    const int l = t & 63;
    const u64 lt = (1ull << l) - 1ull;
    const int base = blockIdx.x * CH + w * 128;

    // ---- Phase A: ballot counts (dst kept in registers) ----
    int dA[2];
    int c0 = 0, c1 = 0, c2 = 0, c3 = 0, c4 = 0, c5 = 0, c6 = 0, c7 = 0;
#pragma unroll
    for (int r = 0; r < 2; ++r) {
        const int i = base + r * 64 + l;
        int d = -1;
        if (i < E) d = dst[i];
        dA[r] = d;
        const int p = (d >= 0) ? (d / Q) : 8;
        c0 += __popcll(__ballot(p == 0));
        c1 += __popcll(__ballot(p == 1));
        c2 += __popcll(__ballot(p == 2));
        c3 += __popcll(__ballot(p == 3));
        c4 += __popcll(__ballot(p == 4));
        c5 += __popcll(__ballot(p == 5));
        c6 += __popcll(__ballot(p == 6));
        c7 += __popcll(__ballot(p == 7));
    }
    if (l == 0) {
        cw[w][0] = c0; cw[w][1] = c1; cw[w][2] = c2; cw[w][3] = c3;
        cw[w][4] = c4; cw[w][5] = c5; cw[w][6] = c6; cw[w][7] = c7;
    }
    __syncthreads();
    if (t < 8) {
        const int p = t;
        const int s0 = cw[0][p], s1 = cw[1][p], s2 = cw[2][p], s3 = cw[3][p];
        const int tot = s0 + s1 + s2 + s3;
        const int b = (tot > 0) ? atomicAdd(&pcur[p], tot) : 0;
        wb[0][p] = b;
        wb[1][p] = b + s0;
        wb[2][p] = b + s0 + s1;
        wb[3][p] = b + s0 + s1 + s2;
    }
    __syncthreads();

    // ---- Phase B: compute offsets via ballot prefix, write records ----
    int r0 = 0, r1 = 0, r2 = 0, r3 = 0, r4 = 0, r5 = 0, r6 = 0, r7 = 0;
#pragma unroll
    for (int r = 0; r < 2; ++r) {
        const int i = base + r * 64 + l;
        const int d = dA[r];
        const int p = (d >= 0) ? (d / Q) : 8;
        const u64 m0 = __ballot(p == 0), m1 = __ballot(p == 1);
        const u64 m2 = __ballot(p == 2), m3 = __ballot(p == 3);
        const u64 m4 = __ballot(p == 4), m5 = __ballot(p == 5);
        const u64 m6 = __ballot(p == 6), m7 = __ballot(p == 7);
        if (d >= 0) {
            const u64 mym = sel8_u64(p, m0, m1, m2, m3, m4, m5, m6, m7);
            const int run = sel8_i(p, r0, r1, r2, r3, r4, r5, r6, r7);
            const int off = wb[w][p] + run + (int)__popcll(mym & lt);
            stg[off] = (u64)(unsigned)src[i] | ((u64)(unsigned)d << 20)
                     | ((u64)f2bf(ew[i]) << 40);
        }
        r0 += __popcll(m0); r1 += __popcll(m1); r2 += __popcll(m2); r3 += __popcll(m3);
        r4 += __popcll(m4); r5 += __popcll(m5); r6 += __popcll(m6); r7 += __popcll(m7);
    }
}

// ---------------------------------------------------------------------------
// Partition-pinned histogram from the bucket: blocks with bid&7==p stream
// bucket p sequentially; counts atomics confined to the partition's ~50KB
// window (one XCD's L2) — same confinement that makes bucket_scatter cheap.
// ---------------------------------------------------------------------------
__global__ void bucket_hist(const u64* __restrict__ stg,
                            const int* __restrict__ pcur, int cap,
                            int* __restrict__ counts) {
    const int p = blockIdx.x & 7;
    const int sub = blockIdx.x >> 3;
    const int nsub = gridDim.x >> 3;
    const int beg = p * cap;
    const int end = pcur[p];
    for (int i = beg + sub * 256 + threadIdx.x; i < end; i += nsub * 256) {
        const int d = (int)((stg[i] >> 20) & 0xFFFFF);
        atomicAdd(&counts[d], 1);
    }
}

// ---------------------------------------------------------------------------
// Partition-pinned scatter from the bucket: random writes confined to the
// partition's ~1.6MB erec window + 50KB pos cursors (L2-resident).
// ---------------------------------------------------------------------------
__global__ void bucket_scatter(const u64* __restrict__ stg,
                               const int* __restrict__ pcur, int cap,
                               int* __restrict__ pos, u64* __restrict__ erec) {
    const int p = blockIdx.x & 7;
    const int sub = blockIdx.x >> 3;
    const int nsub = gridDim.x >> 3;
    const int beg = p * cap;
    const int end = pcur[p];
    for (int i = beg + sub * 256 + threadIdx.x; i < end; i += nsub * 256) {
        const u64 rec = stg[i];
        const int d = (int)((rec >> 20) & 0xFFFFF);
        const int fp = atomicAdd(&pos[d], 1);
        erec[fp] = rec;
    }
}

// ---------------------------------------------------------------------------
// x fp32 -> bf16 into AX[:,128:256]
// ---------------------------------------------------------------------------
__global__ void convert_x(const float* __restrict__ x,
                          unsigned short* __restrict__ AX, int N) {
    int i = blockIdx.x * blockDim.x + threadIdx.x;
    if (i >= N * 32) return;
    const int row = i >> 5;
    const int c4 = (i & 31) * 4;
    float4 v = *reinterpret_cast<const float4*>(x + (size_t)row * 128 + c4);
    unsigned lo = (unsigned)f2bf(v.x) | ((unsigned)f2bf(v.y) << 16);
    unsigned hi = (unsigned)f2bf(v.z) | ((unsigned)f2bf(v.w) << 16);
    *reinterpret_cast<uint2*>(AX + (size_t)row * 256 + 128 + c4) = make_uint2(lo, hi);
}

// ---------------------------------------------------------------------------
// Pack W = [Wr;Ws] (256x128 fp32) into canonical B-fragment order, bf16:
// Wp[((ks*8 + ct)*64 + lane)*8 + j] = W[ks*32 + (lane>>4)*8 + j][ct*16 + (lane&15)]
// ---------------------------------------------------------------------------
__global__ void pack_W(const float* __restrict__ Wr, const float* __restrict__ Ws,
                       unsigned short* __restrict__ Wp) {
    int t = blockIdx.x * blockDim.x + threadIdx.x;   // 0..4095
    if (t >= 4096) return;
    const int lane = t & 63;
    const int ct = (t >> 6) & 7;
    const int ks = t >> 9;
    const int col = ct * 16 + (lane & 15);
    const int kbase = ks * 32 + (lane >> 4) * 8;
    unsigned short v[8];
#pragma unroll
    for (int j = 0; j < 8; ++j) {
        const int k = kbase + j;
        const float w = (k < 128) ? Wr[(size_t)k * 128 + col]
                                  : Ws[(size_t)(k - 128) * 128 + col];
        v[j] = f2bf(w);
    }
    *reinterpret_cast<uint4*>(Wp + (size_t)t * 8) = *reinterpret_cast<uint4*>(v);
}

// ---------------------------------------------------------------------------
// Gather-aggregate v3: one wave per node; lane group g=lane>>4 handles edge
// i+g (16 lanes x 16B = full 256B row); 4-deep unrolled (16 edges in flight).
// Cross-lane reduce (xor 16,32); lanes 0-15 write the agg row.
// Reads AX[:,128:256], writes AX[:,0:128].
// ---------------------------------------------------------------------------
template <bool WEIGHTED>
__global__ void __launch_bounds__(256)
gather_aggregate(const unsigned short* __restrict__ AX,
                 const int* __restrict__ row_ptr,
                 const u64* __restrict__ erec,
                 unsigned short* __restrict__ AXagg,
                 int N) {
    const int node = blockIdx.x * 4 + (threadIdx.x >> 6);
    const int lane = threadIdx.x & 63;
    if (node >= N) return;
    const int g = lane >> 4;      // edge subgroup 0..3
    const int c = lane & 15;      // 16B column -> feats c*8..c*8+7

    const int beg = row_ptr[node];
    const int end = row_ptr[node + 1];

    float acc[8];
#pragma unroll
    for (int j = 0; j < 8; ++j) acc[j] = 0.f;

    auto body = [&](int i) {
        const u64 r = erec[i];
        const float w = WEIGHTED ? bfu((unsigned short)(r >> 40)) : 1.f;
        const uint4 v = *reinterpret_cast<const uint4*>(
            AX + (size_t)(r & 0xFFFFF) * 256 + 128 + c * 8);
        acc[0] += w * bf2f_lo(v.x); acc[1] += w * bf2f_hi(v.x);
        acc[2] += w * bf2f_lo(v.y); acc[3] += w * bf2f_hi(v.y);
        acc[4] += w * bf2f_lo(v.z); acc[5] += w * bf2f_hi(v.z);
        acc[6] += w * bf2f_lo(v.w); acc[7] += w * bf2f_hi(v.w);
    };

    int i = beg + g;
    for (; i + 12 < end; i += 16) { body(i); body(i + 4); body(i + 8); body(i + 12); }
    for (; i < end; i += 4) body(i);

    // reduce across the 4 edge subgroups
#pragma unroll
    for (int j = 0; j < 8; ++j) {
        acc[j] += __shfl_xor(acc[j], 16);
        acc[j] += __shfl_xor(acc[j], 32);
    }

    if (lane < 16) {
        uint4 o;
        o.x = (unsigned)f2bf(acc[0]) | ((unsigned)f2bf(acc[1]) << 16);
        o.y = (unsigned)f2bf(acc[2]) | ((unsigned)f2bf(acc[3]) << 16);
        o.z = (unsigned)f2bf(acc[4]) | ((unsigned)f2bf(acc[5]) << 16);
        o.w = (unsigned)f2bf(acc[6]) | ((unsigned)f2bf(acc[7]) << 16);
        *reinterpret_cast<uint4*>(AXagg + (size_t)node * 256 + c * 8) = o;
    }
}

// ---------------------------------------------------------------------------
// MFMA GEMM: out = relu(AX @ [Wr;Ws] + br), K=256, bf16 in, fp32 acc.
// Wave = 32 rows x 128 cols (2x8 fragments of 16x16x32). A direct from global.
// ---------------------------------------------------------------------------
template <bool TO_BF16>
__global__ void __launch_bounds__(256)
gemm_mfma(const unsigned short* __restrict__ AX,
          const unsigned short* __restrict__ Wp,
          const float* __restrict__ br,
          float* __restrict__ out,
          unsigned short* __restrict__ AXh,
          int N) {
    const int tid = threadIdx.x;
    const int wave = tid >> 6;
    const int lane = tid & 63;
    const int r0 = blockIdx.x * 128 + wave * 32;
    const int lk = (lane >> 4) * 8;

    int ra = r0 + (lane & 15);
    int rb = ra + 16;
    if (ra >= N) ra = N - 1;   // clamped loads; stores guarded below
    if (rb >= N) rb = N - 1;
    const unsigned short* pa = AX + (size_t)ra * 256 + lk;
    const unsigned short* pb = AX + (size_t)rb * 256 + lk;
    const unsigned short* pw = Wp + (size_t)lane * 8;

    f32x4 acc[2][8];
#pragma unroll
    for (int rt = 0; rt < 2; ++rt)
#pragma unroll
        for (int ct = 0; ct < 8; ++ct)
            acc[rt][ct] = (f32x4){0.f, 0.f, 0.f, 0.f};

#pragma unroll
    for (int ks = 0; ks < 8; ++ks) {
        const bf16x8 a0 = *reinterpret_cast<const bf16x8*>(pa + ks * 32);
        const bf16x8 a1 = *reinterpret_cast<const bf16x8*>(pb + ks * 32);
#pragma unroll
        for (int ct = 0; ct < 8; ++ct) {
            const bf16x8 b = *reinterpret_cast<const bf16x8*>(pw + (((ks << 3) + ct) << 9));
            acc[0][ct] = __builtin_amdgcn_mfma_f32_16x16x32_bf16(a0, b, acc[0][ct], 0, 0, 0);
            acc[1][ct] = __builtin_amdgcn_mfma_f32_16x16x32_bf16(a1, b, acc[1][ct], 0, 0, 0);
        }
    }

    const int crow = (lane >> 4) * 4;
    const int ccol = lane & 15;
#pragma unroll
    for (int ct = 0; ct < 8; ++ct) {
        const int col = ct * 16 + ccol;
        const float bias = br[col];
#pragma unroll
        for (int rt = 0; rt < 2; ++rt) {
#pragma unroll
            for (int reg = 0; reg < 4; ++reg) {
                const int row = r0 + rt * 16 + crow + reg;
                if (row >= N) continue;
                const float v = fmaxf(acc[rt][ct][reg] + bias, 0.f);
                if (TO_BF16) {
                    AXh[(size_t)row * 256 + 128 + col] = f2bf(v);
                } else {
                    out[(size_t)row * 128 + col] = v;
                }
            }
        }
    }
}

extern "C" void kernel_launch(void* const* d_in, const int* in_sizes, int n_in,
                              void* d_out, int out_size, void* d_ws, size_t ws_size,
                              hipStream_t stream) {
    const float* x  = (const float*)d_in[0];
    const int*   ei = (const int*)d_in[1];     // [2, E] int32 (JAX x64 disabled)
    const float* ew = (const float*)d_in[2];
    const float* Wr0 = (const float*)d_in[3];
    const float* br0 = (const float*)d_in[4];
    const float* Ws0 = (const float*)d_in[5];
    const float* Wr1 = (const float*)d_in[6];
    const float* br1 = (const float*)d_in[7];
    const float* Ws1 = (const float*)d_in[8];

    const int N = in_sizes[0] / D_FEAT;
    const int E = in_sizes[1] / 2;
    const int* src = ei;
    const int* dst = ei + E;
    const int Q = (N + 7) / 8;              // dst-partition width
    const int cap = E / 8 + 65536;          // slack-reserved bucket capacity

    // ---- workspace carve-up (16B aligned), ~83 MB ----
    char* w = (char*)d_ws;
    auto carve = [&](size_t bytes) { char* p = w; w += (bytes + 15) & ~(size_t)15; return p; };
    unsigned short* AX  = (unsigned short*)carve((size_t)N * 256 * 2);  // 51.2 MB
    unsigned short* Wp0 = (unsigned short*)carve(256 * 128 * 2);
    unsigned short* Wp1 = (unsigned short*)carve(256 * 128 * 2);
    int*   counts  = (int*)  carve((size_t)N * 4);
    int*   row_ptr = (int*)  carve((size_t)(N + 1) * 4);
    int*   pos     = (int*)  carve((size_t)N * 4);
    int*   bsum    = (int*)  carve(128 * 4);
    int*   pcur    = (int*)  carve(8 * 4);
    u64*   stg     = (u64*)  carve((size_t)cap * 8 * 8);                // 17 MB
    u64*   erec    = (u64*)  carve((size_t)E * 8);                      // 12.8 MB

    float* out = (float*)d_out;

    const int nb = (N + 1023) / 1024;
    const int nchunk = (E + CH - 1) / CH;
    const int gather_blocks = (N + 3) / 4;
    const int gemm_blocks = (N + 127) / 128;

    // ---- one-time prep (independent of edges) ----
    convert_x<<<(N * 32 + 255) / 256, 256, 0, stream>>>(x, AX, N);
    pack_W<<<16, 256, 0, stream>>>(Wr0, Ws0, Wp0);
    pack_W<<<16, 256, 0, stream>>>(Wr1, Ws1, Wp1);

    // ---- edge pipeline: split -> bucket hist -> scans -> bucket scatter ----
    hipMemsetAsync(counts, 0, (size_t)N * 4, stream);
    init_pcur<<<1, 64, 0, stream>>>(pcur, cap);
    split_edges<<<nchunk, 256, 0, stream>>>(src, dst, ew, E, Q, pcur, stg);
    bucket_hist<<<2048, 256, 0, stream>>>(stg, pcur, cap, counts);
    scan_block_sums<<<nb, 256, 0, stream>>>(counts, bsum, N);
    scan_offsets<<<1, 128, 0, stream>>>(bsum, nb, row_ptr, N);
    scan_final<<<nb, 256, 0, stream>>>(counts, bsum, row_ptr, pos, N);
    bucket_scatter<<<2048, 256, 0, stream>>>(stg, pcur, cap, pos, erec);

    // ---- Layer 0 (weighted) ----
    gather_aggregate<true><<<gather_blocks, 256, 0, stream>>>(AX, row_ptr, erec, AX, N);
    gemm_mfma<true><<<gemm_blocks, 256, 0, stream>>>(AX, Wp0, br0, nullptr, AX, N);

    // ---- Layer 1 (unweighted — reference omits edge_weight here) ----
    gather_aggregate<false><<<gather_blocks, 256, 0, stream>>>(AX, row_ptr, erec, AX, N);
    gemm_mfma<false><<<gemm_blocks, 256, 0, stream>>>(AX, Wp1, br1, out, nullptr, N);
}

// Round 13
// 300.367 us; speedup vs baseline: 1.3637x; 1.3637x over previous
//
#include <hip/hip_runtime.h>
#include <hip/hip_bf16.h>

#ifndef D_FEAT
#define D_FEAT 128
#endif

#define SLOTS 40          // ELL width: Poisson(16) + 6 sigma
#define OVF_CAP 8192

typedef __attribute__((ext_vector_type(8))) short bf16x8;
typedef __attribute__((ext_vector_type(4))) float f32x4;
typedef unsigned long long u64;

// ---------------- bf16 helpers (RN-even) ----------------
__device__ __forceinline__ unsigned short f2bf(float f) {
    union { float f; unsigned u; } v; v.f = f;
    unsigned r = v.u + 0x7FFF + ((v.u >> 16) & 1);
    return (unsigned short)(r >> 16);
}
__device__ __forceinline__ float bf2f_lo(unsigned u) {
    union { unsigned u; float f; } v; v.u = u << 16; return v.f;
}
__device__ __forceinline__ float bf2f_hi(unsigned u) {
    union { unsigned u; float f; } v; v.u = u & 0xFFFF0000u; return v.f;
}

// ---------------------------------------------------------------------------
// ELL scatter, partition-pinned (p = bid&7): blocks re-scan the edge list and
// take only their dst-range; pos[d] is both insert cursor and final degree.
// Record: {u32 src, f32 w}. Overflow (slot>=SLOTS) goes to a tiny list.
// ---------------------------------------------------------------------------
__global__ void scatter_ell(const int* __restrict__ src, const int* __restrict__ dst,
                            const float* __restrict__ ew, int E, int Q, int N,
                            int* __restrict__ pos, uint2* __restrict__ ell,
                            int* __restrict__ ovf_cnt, int4* __restrict__ ovf) {
    const int p = blockIdx.x & 7;
    const int sub = blockIdx.x >> 3;
    const int nsub = gridDim.x >> 3;
    const int lo = p * Q;
    const int hi = min(lo + Q, N);
    for (int i = sub * 256 + threadIdx.x; i < E; i += nsub * 256) {
        const int d = dst[i];
        if (d >= lo && d < hi) {
            const int slot = atomicAdd(&pos[d], 1);
            if (slot < SLOTS) {
                ell[(size_t)d * SLOTS + slot] =
                    make_uint2((unsigned)src[i], __float_as_uint(ew[i]));
            } else {
                const int o = atomicAdd(ovf_cnt, 1);
                if (o < OVF_CAP)
                    ovf[o] = make_int4(src[i], d, __float_as_int(ew[i]), 0);
            }
        }
    }
}

// ---------------------------------------------------------------------------
// Overflow fixup: ONE wave, edges processed serially (program-order safe for
// repeated same-dst edges). Each lane covers 2 bf16 feats (64x4B = 256B row).
// agg[d] += w * XH[src]  (bf16 read-modify-write; overflow count ~0-tens).
// ---------------------------------------------------------------------------
template <bool WEIGHTED>
__global__ void ovf_fixup(const unsigned short* __restrict__ AX,
                          const int* __restrict__ ovf_cnt,
                          const int4* __restrict__ ovf,
                          unsigned short* __restrict__ AXagg) {
    const int n = min(*ovf_cnt, OVF_CAP);
    const int lane = threadIdx.x;   // 64 threads
    for (int e = 0; e < n; ++e) {
        const int4 r = ovf[e];
        const float w = WEIGHTED ? __int_as_float(r.z) : 1.f;
        const unsigned u = *reinterpret_cast<const unsigned*>(
            AX + (size_t)(unsigned)r.x * 256 + 128 + lane * 2);
        unsigned* pa = reinterpret_cast<unsigned*>(
            AXagg + (size_t)r.y * 256 + lane * 2);
        const unsigned cur = *pa;
        const float ax = bf2f_lo(cur) + w * bf2f_lo(u);
        const float ay = bf2f_hi(cur) + w * bf2f_hi(u);
        *pa = (unsigned)f2bf(ax) | ((unsigned)f2bf(ay) << 16);
    }
}

// ---------------------------------------------------------------------------
// x fp32 -> bf16 into AX[:,128:256]
// ---------------------------------------------------------------------------
__global__ void convert_x(const float* __restrict__ x,
                          unsigned short* __restrict__ AX, int N) {
    int i = blockIdx.x * blockDim.x + threadIdx.x;
    if (i >= N * 32) return;
    const int row = i >> 5;
    const int c4 = (i & 31) * 4;
    float4 v = *reinterpret_cast<const float4*>(x + (size_t)row * 128 + c4);
    unsigned lo = (unsigned)f2bf(v.x) | ((unsigned)f2bf(v.y) << 16);
    unsigned hi = (unsigned)f2bf(v.z) | ((unsigned)f2bf(v.w) << 16);
    *reinterpret_cast<uint2*>(AX + (size_t)row * 256 + 128 + c4) = make_uint2(lo, hi);
}

// ---------------------------------------------------------------------------
// Pack W = [Wr;Ws] (256x128 fp32) into canonical B-fragment order, bf16:
// Wp[((ks*8 + ct)*64 + lane)*8 + j] = W[ks*32 + (lane>>4)*8 + j][ct*16 + (lane&15)]
// ---------------------------------------------------------------------------
__global__ void pack_W(const float* __restrict__ Wr, const float* __restrict__ Ws,
                       unsigned short* __restrict__ Wp) {
    int t = blockIdx.x * blockDim.x + threadIdx.x;   // 0..4095
    if (t >= 4096) return;
    const int lane = t & 63;
    const int ct = (t >> 6) & 7;
    const int ks = t >> 9;
    const int col = ct * 16 + (lane & 15);
    const int kbase = ks * 32 + (lane >> 4) * 8;
    unsigned short v[8];
#pragma unroll
    for (int j = 0; j < 8; ++j) {
        const int k = kbase + j;
        const float w = (k < 128) ? Wr[(size_t)k * 128 + col]
                                  : Ws[(size_t)(k - 128) * 128 + col];
        v[j] = f2bf(w);
    }
    *reinterpret_cast<uint4*>(Wp + (size_t)t * 8) = *reinterpret_cast<uint4*>(v);
}

// ---------------------------------------------------------------------------
// Gather-aggregate (ELL): one wave per node; lane group g=lane>>4 handles
// edge i+g (16 lanes x 16B = full 256B row); 4-deep unrolled.
// Cross-lane reduce (xor 16,32); lanes 0-15 write the agg row.
// Reads AX[:,128:256], writes AX[:,0:128].
// ---------------------------------------------------------------------------
template <bool WEIGHTED>
__global__ void __launch_bounds__(256)
gather_ell(const unsigned short* __restrict__ AX,
           const int* __restrict__ pos,
           const uint2* __restrict__ ell,
           unsigned short* __restrict__ AXagg,
           int N) {
    const int node = blockIdx.x * 4 + (threadIdx.x >> 6);
    const int lane = threadIdx.x & 63;
    if (node >= N) return;
    const int g = lane >> 4;      // edge subgroup 0..3
    const int c = lane & 15;      // 16B column -> feats c*8..c*8+7

    const int deg = min(pos[node], SLOTS);
    const uint2* ebase = ell + (size_t)node * SLOTS;

    float acc[8];
#pragma unroll
    for (int j = 0; j < 8; ++j) acc[j] = 0.f;

    auto body = [&](int i) {
        const uint2 r = ebase[i];
        const float w = WEIGHTED ? __uint_as_float(r.y) : 1.f;
        const uint4 v = *reinterpret_cast<const uint4*>(
            AX + (size_t)r.x * 256 + 128 + c * 8);
        acc[0] += w * bf2f_lo(v.x); acc[1] += w * bf2f_hi(v.x);
        acc[2] += w * bf2f_lo(v.y); acc[3] += w * bf2f_hi(v.y);
        acc[4] += w * bf2f_lo(v.z); acc[5] += w * bf2f_hi(v.z);
        acc[6] += w * bf2f_lo(v.w); acc[7] += w * bf2f_hi(v.w);
    };

    int i = g;
    for (; i + 12 < deg; i += 16) { body(i); body(i + 4); body(i + 8); body(i + 12); }
    for (; i < deg; i += 4) body(i);

    // reduce across the 4 edge subgroups
#pragma unroll
    for (int j = 0; j < 8; ++j) {
        acc[j] += __shfl_xor(acc[j], 16);
        acc[j] += __shfl_xor(acc[j], 32);
    }

    if (lane < 16) {
        uint4 o;
        o.x = (unsigned)f2bf(acc[0]) | ((unsigned)f2bf(acc[1]) << 16);
        o.y = (unsigned)f2bf(acc[2]) | ((unsigned)f2bf(acc[3]) << 16);
        o.z = (unsigned)f2bf(acc[4]) | ((unsigned)f2bf(acc[5]) << 16);
        o.w = (unsigned)f2bf(acc[6]) | ((unsigned)f2bf(acc[7]) << 16);
        *reinterpret_cast<uint4*>(AXagg + (size_t)node * 256 + c * 8) = o;
    }
}

// ---------------------------------------------------------------------------
// MFMA GEMM: out = relu(AX @ [Wr;Ws] + br), K=256, bf16 in, fp32 acc.
// Wave = 32 rows x 128 cols (2x8 fragments of 16x16x32). A direct from global.
// ---------------------------------------------------------------------------
template <bool TO_BF16>
__global__ void __launch_bounds__(256)
gemm_mfma(const unsigned short* __restrict__ AX,
          const unsigned short* __restrict__ Wp,
          const float* __restrict__ br,
          float* __restrict__ out,
          unsigned short* __restrict__ AXh,
          int N) {
    const int tid = threadIdx.x;
    const int wave = tid >> 6;
    const int lane = tid & 63;
    const int r0 = blockIdx.x * 128 + wave * 32;
    const int lk = (lane >> 4) * 8;

    int ra = r0 + (lane & 15);
    int rb = ra + 16;
    if (ra >= N) ra = N - 1;   // clamped loads; stores guarded below
    if (rb >= N) rb = N - 1;
    const unsigned short* pa = AX + (size_t)ra * 256 + lk;
    const unsigned short* pb = AX + (size_t)rb * 256 + lk;
    const unsigned short* pw = Wp + (size_t)lane * 8;

    f32x4 acc[2][8];
#pragma unroll
    for (int rt = 0; rt < 2; ++rt)
#pragma unroll
        for (int ct = 0; ct < 8; ++ct)
            acc[rt][ct] = (f32x4){0.f, 0.f, 0.f, 0.f};

#pragma unroll
    for (int ks = 0; ks < 8; ++ks) {
        const bf16x8 a0 = *reinterpret_cast<const bf16x8*>(pa + ks * 32);
        const bf16x8 a1 = *reinterpret_cast<const bf16x8*>(pb + ks * 32);
#pragma unroll
        for (int ct = 0; ct < 8; ++ct) {
            const bf16x8 b = *reinterpret_cast<const bf16x8*>(pw + (((ks << 3) + ct) << 9));
            acc[0][ct] = __builtin_amdgcn_mfma_f32_16x16x32_bf16(a0, b, acc[0][ct], 0, 0, 0);
            acc[1][ct] = __builtin_amdgcn_mfma_f32_16x16x32_bf16(a1, b, acc[1][ct], 0, 0, 0);
        }
    }

    const int crow = (lane >> 4) * 4;
    const int ccol = lane & 15;
#pragma unroll
    for (int ct = 0; ct < 8; ++ct) {
        const int col = ct * 16 + ccol;
        const float bias = br[col];
#pragma unroll
        for (int rt = 0; rt < 2; ++rt) {
#pragma unroll
            for (int reg = 0; reg < 4; ++reg) {
                const int row = r0 + rt * 16 + crow + reg;
                if (row >= N) continue;
                const float v = fmaxf(acc[rt][ct][reg] + bias, 0.f);
                if (TO_BF16) {
                    AXh[(size_t)row * 256 + 128 + col] = f2bf(v);
                } else {
                    out[(size_t)row * 128 + col] = v;
                }
            }
        }
    }
}

extern "C" void kernel_launch(void* const* d_in, const int* in_sizes, int n_in,
                              void* d_out, int out_size, void* d_ws, size_t ws_size,
                              hipStream_t stream) {
    const float* x  = (const float*)d_in[0];
    const int*   ei = (const int*)d_in[1];     // [2, E] int32 (JAX x64 disabled)
    const float* ew = (const float*)d_in[2];
    const float* Wr0 = (const float*)d_in[3];
    const float* br0 = (const float*)d_in[4];
    const float* Ws0 = (const float*)d_in[5];
    const float* Wr1 = (const float*)d_in[6];
    const float* br1 = (const float*)d_in[7];
    const float* Ws1 = (const float*)d_in[8];

    const int N = in_sizes[0] / D_FEAT;
    const int E = in_sizes[1] / 2;
    const int* src = ei;
    const int* dst = ei + E;
    const int Q = (N + 7) / 8;              // dst-partition width

    // ---- workspace carve-up (16B aligned), ~84 MB ----
    char* w = (char*)d_ws;
    auto carve = [&](size_t bytes) { char* p = w; w += (bytes + 15) & ~(size_t)15; return p; };
    unsigned short* AX  = (unsigned short*)carve((size_t)N * 256 * 2);    // 51.2 MB
    unsigned short* Wp0 = (unsigned short*)carve(256 * 128 * 2);
    unsigned short* Wp1 = (unsigned short*)carve(256 * 128 * 2);
    int*   pos     = (int*)  carve((size_t)N * 4);                        // 0.4 MB
    int*   ovf_cnt = (int*)  carve(16);
    int4*  ovf     = (int4*) carve((size_t)OVF_CAP * 16);                 // 128 KB
    uint2* ell     = (uint2*)carve((size_t)N * SLOTS * 8);                // 32 MB

    float* out = (float*)d_out;

    const int gather_blocks = (N + 3) / 4;
    const int gemm_blocks = (N + 127) / 128;

    // ---- one-time prep (independent of edges) ----
    convert_x<<<(N * 32 + 255) / 256, 256, 0, stream>>>(x, AX, N);
    pack_W<<<16, 256, 0, stream>>>(Wr0, Ws0, Wp0);
    pack_W<<<16, 256, 0, stream>>>(Wr1, Ws1, Wp1);

    // ---- edge pipeline: just one partition-pinned ELL scatter ----
    hipMemsetAsync(pos, 0, (size_t)N * 4, stream);
    hipMemsetAsync(ovf_cnt, 0, 4, stream);
    scatter_ell<<<2048, 256, 0, stream>>>(src, dst, ew, E, Q, N, pos, ell, ovf_cnt, ovf);

    // ---- Layer 0 (weighted) ----
    gather_ell<true><<<gather_blocks, 256, 0, stream>>>(AX, pos, ell, AX, N);
    ovf_fixup<true><<<1, 64, 0, stream>>>(AX, ovf_cnt, ovf, AX);
    gemm_mfma<true><<<gemm_blocks, 256, 0, stream>>>(AX, Wp0, br0, nullptr, AX, N);

    // ---- Layer 1 (unweighted — reference omits edge_weight here) ----
    gather_ell<false><<<gather_blocks, 256, 0, stream>>>(AX, pos, ell, AX, N);
    ovf_fixup<false><<<1, 64, 0, stream>>>(AX, ovf_cnt, ovf, AX);
    gemm_mfma<false><<<gemm_blocks, 256, 0, stream>>>(AX, Wp1, br1, out, nullptr, N);
}